// Round 3
// baseline (1767.328 us; speedup 1.0000x reference)
//
#include <hip/hip_runtime.h>

// Edge2Node via on-the-fly CSR + gather (no f32 atomics).
//
// Round-2 post-mortem: fused atomic-scatter was atomic-message-bound
// (WRITE_SIZE=900MB = 204.8M 4B atomic messages; VALUBusy 22%, HBM 18%).
// This version builds adjacency lists (counting sort over 2N bins: src bins
// [0,N), dst bins [N,2N)) with only 6.4M int atomics, then gathers per node:
// one WAVE per node, lane j owns output column j, h=relu(x@W+b) recomputed
// per edge-visit from uniform (scalar) x-row loads. Sums stay in registers;
// the only f32 global writes are the final output.

__global__ __launch_bounds__(256) void hist_kernel(
    const int* __restrict__ ei, int* __restrict__ cnt, int twoE, int E, int N)
{
    int i = blockIdx.x * blockDim.x + threadIdx.x;
    int stride = gridDim.x * blockDim.x;
    for (; i < twoE; i += stride) {
        int node = ei[i] + ((i < E) ? 0 : N);
        atomicAdd(&cnt[node], 1);
    }
}

__global__ __launch_bounds__(1024) void scan_partial_kernel(
    const int* __restrict__ cnt, int* __restrict__ offl,
    int* __restrict__ bsum, int n)
{
    __shared__ int s[1024];
    const int t = threadIdx.x;
    const int i = blockIdx.x * 1024 + t;
    const int v = (i < n) ? cnt[i] : 0;
    s[t] = v;
    __syncthreads();
#pragma unroll
    for (int st = 1; st < 1024; st <<= 1) {
        int add = (t >= st) ? s[t - st] : 0;
        __syncthreads();
        s[t] += add;
        __syncthreads();
    }
    if (i < n) offl[i] = s[t] - v;          // exclusive within block
    if (t == 1023) bsum[blockIdx.x] = s[t]; // block total
}

__global__ __launch_bounds__(1024) void scan_blocks_kernel(int* bsum, int B)
{
    __shared__ int s[1024];
    const int t = threadIdx.x;
    const int v = (t < B) ? bsum[t] : 0;
    s[t] = v;
    __syncthreads();
#pragma unroll
    for (int st = 1; st < 1024; st <<= 1) {
        int add = (t >= st) ? s[t - st] : 0;
        __syncthreads();
        s[t] += add;
        __syncthreads();
    }
    if (t < B) bsum[t] = s[t] - v;          // exclusive block prefix
}

__global__ __launch_bounds__(256) void finalize_kernel(
    const int* __restrict__ offl, const int* __restrict__ bsum,
    int* __restrict__ off, int* __restrict__ cur, int n)
{
    int i = blockIdx.x * blockDim.x + threadIdx.x;
    if (i >= n) return;
    int o = offl[i] + bsum[i >> 10];
    off[i] = o;
    cur[i] = o;
}

__global__ __launch_bounds__(256) void fill_kernel(
    const int* __restrict__ ei, int* __restrict__ cur,
    int* __restrict__ adj, int twoE, int E, int N)
{
    int i = blockIdx.x * blockDim.x + threadIdx.x;
    int stride = gridDim.x * blockDim.x;
    for (; i < twoE; i += stride) {
        int node = ei[i] + ((i < E) ? 0 : N);
        int pos = atomicAdd(&cur[node], 1);
        adj[pos] = (i < E) ? i : (i - E);   // store edge id
    }
}

__device__ __forceinline__ float edge_h(const float* __restrict__ xrow,
                                        const float w[64], float bj)
{
    const float4* __restrict__ r = (const float4*)xrow;
    float a0 = bj, a1 = 0.f, a2 = 0.f, a3 = 0.f;
#pragma unroll
    for (int k4 = 0; k4 < 16; ++k4) {
        const float4 v = r[k4];
        a0 = fmaf(v.x, w[4 * k4 + 0], a0);
        a1 = fmaf(v.y, w[4 * k4 + 1], a1);
        a2 = fmaf(v.z, w[4 * k4 + 2], a2);
        a3 = fmaf(v.w, w[4 * k4 + 3], a3);
    }
    return fmaxf((a0 + a1) + (a2 + a3), 0.f);
}

__device__ __forceinline__ float seg_accum(const float* __restrict__ x,
                                           const int* __restrict__ adj,
                                           int base, int c,
                                           const float w[64], float bj)
{
    float acc = 0.f;
    int i = 0;
    for (; i + 2 <= c; i += 2) {            // 2-way ILP across edges
        int e0 = __builtin_amdgcn_readfirstlane(adj[base + i]);
        int e1 = __builtin_amdgcn_readfirstlane(adj[base + i + 1]);
        float h0 = edge_h(x + (size_t)e0 * 64, w, bj);
        float h1 = edge_h(x + (size_t)e1 * 64, w, bj);
        acc += h0 + h1;
    }
    if (i < c) {
        int e0 = __builtin_amdgcn_readfirstlane(adj[base + i]);
        acc += edge_h(x + (size_t)e0 * 64, w, bj);
    }
    return acc;
}

__global__ __launch_bounds__(256) void gather_kernel(
    const float* __restrict__ x,       // [E,64]
    const int*   __restrict__ adj,     // [2E] edge ids
    const int*   __restrict__ off,     // [2N]
    const int*   __restrict__ cnt,     // [2N]
    const float* __restrict__ W,       // [64,64]
    const float* __restrict__ bias,    // [64]
    float* __restrict__ out,           // [N,64]
    int N)
{
    const int lane          = threadIdx.x & 63;
    const int wave_in_blk   = threadIdx.x >> 6;
    const int waves_per_blk = blockDim.x >> 6;
    const int gwave  = blockIdx.x * waves_per_blk + wave_in_blk;
    const int nwaves = gridDim.x * waves_per_blk;

    float w[64];
#pragma unroll
    for (int k = 0; k < 64; ++k) w[k] = W[k * 64 + lane];
    const float bj = bias[lane];

    for (int n = gwave; n < N; n += nwaves) {
        const int b0 = off[n],     c0 = cnt[n];
        const int b1 = off[N + n], c1 = cnt[N + n];
        const float a_s = seg_accum(x, adj, b0, c0, w, bj);
        const float a_d = seg_accum(x, adj, b1, c1, w, bj);
        const float r = 0.5f * (a_s / fmaxf((float)c0, 1.f) +
                                a_d / fmaxf((float)c1, 1.f));
        out[(size_t)n * 64 + lane] = r;
    }
}

extern "C" void kernel_launch(void* const* d_in, const int* in_sizes, int n_in,
                              void* d_out, int out_size, void* d_ws, size_t ws_size,
                              hipStream_t stream)
{
    const float* x  = (const float*)d_in[0];   // [E,64]
    const int*   ei = (const int*)d_in[1];     // [2,E] flat: src then dst
    const float* W  = (const float*)d_in[3];   // [64,64]
    const float* b  = (const float*)d_in[4];   // [64]

    const int E    = in_sizes[0] / 64;
    const int N    = out_size / 64;
    const int twoE = 2 * E;
    const int twoN = 2 * N;

    int* cnt  = (int*)d_ws;       // [2N]
    int* offl = cnt  + twoN;      // [2N]
    int* off  = offl + twoN;      // [2N]
    int* cur  = off  + twoN;      // [2N]
    int* bsum = cur  + twoN;      // [1024]
    int* adj  = bsum + 1024;      // [2E]

    hipMemsetAsync(cnt, 0, (size_t)twoN * sizeof(int), stream);

    hist_kernel<<<2048, 256, 0, stream>>>(ei, cnt, twoE, E, N);

    const int B = (twoN + 1023) / 1024;        // 196 for N=100K (<=1024)
    scan_partial_kernel<<<B, 1024, 0, stream>>>(cnt, offl, bsum, twoN);
    scan_blocks_kernel<<<1, 1024, 0, stream>>>(bsum, B);
    finalize_kernel<<<(twoN + 255) / 256, 256, 0, stream>>>(offl, bsum, off, cur, twoN);

    fill_kernel<<<2048, 256, 0, stream>>>(ei, cur, adj, twoE, E, N);

    gather_kernel<<<2560, 256, 0, stream>>>(x, adj, off, cnt, W, b,
                                            (float*)d_out, N);
}